// Round 8
// baseline (341.135 us; speedup 1.0000x reference)
//
#include <hip/hip_runtime.h>
#include <math.h>

// Output = Re(H) as float32, shape (B,8,8) row-major, 64 floats = 16 float4/record.
// H rows 0-3 = [0|I]; rows 4-7 = [L11 | L12], L12 purely imaginary -> Re = 0.
// Re(L11) needs only c1 = cos(sqrt3*kx), c2 = cos(sqrt3/2*kx + 1.5*ky):
//   m00r = -(0.75 + 0.75*c1)   offr = -sqrt3/4*(1-c1)   m11r = -(0.25+0.25*c1+c2)
// Quads: q1=(1,0,0,0) q3=(0,1,0,0) q5=(0,0,1,0) q7=(0,0,0,1)
//        q8=(1.5,0,m00r,offr) q10=(0,1.5,offr,m11r)
//        q12=(m00r,offr,1.5,0) q14=(offr,m11r,0,1.5); all others zero.
//
// NOTE: this round launches the kernel TWICE (idempotent) purely to measure
// the kernel's own duration as dur_r7 - dur_r5; harness poison fills dominate
// the timed region otherwise and crowd the kernel out of rocprof top-5.

typedef float vf4 __attribute__((ext_vector_type(4)));

#define SQRT3F 1.73205080756887729f
#define S34F   0.43301270189221933f   // sqrt(3)/4

__global__ void __launch_bounds__(256)
bulk_hamiltonian_real_kernel(const float* __restrict__ k, vf4* __restrict__ out,
                             int n4) {
    const int i = blockIdx.x * blockDim.x + threadIdx.x;
    if (i >= n4) return;
    const int b = i >> 4;   // record index
    const int q = i & 15;   // float4 index within record
    vf4 v = (vf4)(0.0f);
    if ((q & 9) == 8) {     // q in {8,10,12,14}: the k-dependent quads
        const float kx = k[2 * (size_t)b];
        const float ky = k[2 * (size_t)b + 1];
        const float c1 = cosf(kx * SQRT3F);
        const float c2 = cosf(kx * (0.5f * SQRT3F) + ky * 1.5f);
        const float m00r = -(0.75f + 0.75f * c1);
        const float offr = -S34F * (1.0f - c1);
        const float m11r = -(0.25f + 0.25f * c1 + c2);
        if (q == 8)       { v.x = 1.5f; v.z = m00r; v.w = offr; }
        else if (q == 10) { v.y = 1.5f; v.z = offr; v.w = m11r; }
        else if (q == 12) { v.x = m00r; v.y = offr; v.z = 1.5f; }
        else              { v.x = offr; v.y = m11r; v.w = 1.5f; }
    } else {
        // identity block: q=1,3,5,7 -> unit in slot q>>1; everything else zero
        const float one = (q < 8 && (q & 1)) ? 1.0f : 0.0f;
        const int h = q >> 1;
        v.x = (h == 0) ? one : 0.0f;
        v.y = (h == 1) ? one : 0.0f;
        v.z = (h == 2) ? one : 0.0f;
        v.w = (h == 3) ? one : 0.0f;
    }
    out[i] = v;
}

extern "C" void kernel_launch(void* const* d_in, const int* in_sizes, int n_in,
                              void* d_out, int out_size, void* d_ws, size_t ws_size,
                              hipStream_t stream) {
    const float* k = (const float*)d_in[0];
    const long long B = in_sizes[0] / 2;     // k is (B,2,1) float32
    long long n4_ll = B * 16;                // 64 floats = 16 float4 per record
    const long long n4_guar = (long long)out_size / 4;   // guaranteed floats/4
    if (n4_guar > 0 && n4_guar < n4_ll) n4_ll = n4_guar;
    if (n4_ll <= 0) return;
    const int n4 = (int)n4_ll;
    const int block = 256;
    const int grid = (int)((n4_ll + block - 1) / block);
    // Launch TWICE: second dispatch rewrites identical values (idempotent).
    // T_kernel = dur(this round) - dur(round 5), after fill-BW normalization.
    bulk_hamiltonian_real_kernel<<<grid, block, 0, stream>>>(k, (vf4*)d_out, n4);
    bulk_hamiltonian_real_kernel<<<grid, block, 0, stream>>>(k, (vf4*)d_out, n4);
}

// Round 13
// 270.689 us; speedup vs baseline: 1.2602x; 1.2602x over previous
//
#include <hip/hip_runtime.h>
#include <math.h>

// Output = Re(H) as float32, shape (B,8,8) row-major, 64 floats = 16 float4/record.
// H rows 0-3 = [0|I]; rows 4-7 = [L11 | L12], L12 purely imaginary -> Re = 0.
// Re(L11) needs only c1 = cos(sqrt3*kx), c2 = cos(sqrt3/2*kx + 1.5*ky):
//   m00r = -(0.75 + 0.75*c1)   offr = -sqrt3/4*(1-c1)   m11r = -(0.25+0.25*c1+c2)
// Quads: q1=(1,0,0,0) q3=(0,1,0,0) q5=(0,0,1,0) q7=(0,0,0,1)
//        q8=(1.5,0,m00r,offr) q10=(0,1.5,offr,m11r)
//        q12=(m00r,offr,1.5,0) q14=(offr,m11r,0,1.5); all others zero.
//
// R8 measurement: one launch ~= 76 us (3.4 TB/s) vs 40 us write floor; theory:
// masked libm cosf (2x ~40 instr) serializes the wave past its HBM time.
// This round: __cosf (v_cos_f32; absmax 0.0078 proven in R6) + plain stores.

typedef float vf4 __attribute__((ext_vector_type(4)));

#define SQRT3F 1.73205080756887729f
#define S34F   0.43301270189221933f   // sqrt(3)/4

__global__ void __launch_bounds__(256)
bulk_hamiltonian_real_kernel(const float* __restrict__ k, vf4* __restrict__ out,
                             int n4) {
    const int i = blockIdx.x * blockDim.x + threadIdx.x;
    if (i >= n4) return;
    const int b = i >> 4;   // record index
    const int q = i & 15;   // float4 index within record
    vf4 v = (vf4)(0.0f);
    if ((q & 9) == 8) {     // q in {8,10,12,14}: the k-dependent quads
        const float kx = k[2 * (size_t)b];
        const float ky = k[2 * (size_t)b + 1];
        const float c1 = __cosf(kx * SQRT3F);                      // v_cos_f32
        const float c2 = __cosf(fmaf(ky, 1.5f, kx * (0.5f * SQRT3F)));
        const float m00r = fmaf(-0.75f, c1, -0.75f);
        const float offr = fmaf(S34F, c1, -S34F);
        const float m11r = -fmaf(0.25f, c1, 0.25f + c2);
        if (q == 8)       { v.x = 1.5f; v.z = m00r; v.w = offr; }
        else if (q == 10) { v.y = 1.5f; v.z = offr; v.w = m11r; }
        else if (q == 12) { v.x = m00r; v.y = offr; v.z = 1.5f; }
        else              { v.x = offr; v.y = m11r; v.w = 1.5f; }
    } else {
        // identity block: q=1,3,5,7 -> unit in slot q>>1; everything else zero
        const float one = (q < 8 && (q & 1)) ? 1.0f : 0.0f;
        const int h = q >> 1;
        v.x = (h == 0) ? one : 0.0f;
        v.y = (h == 1) ? one : 0.0f;
        v.z = (h == 2) ? one : 0.0f;
        v.w = (h == 3) ? one : 0.0f;
    }
    out[i] = v;
}

extern "C" void kernel_launch(void* const* d_in, const int* in_sizes, int n_in,
                              void* d_out, int out_size, void* d_ws, size_t ws_size,
                              hipStream_t stream) {
    const float* k = (const float*)d_in[0];
    const long long B = in_sizes[0] / 2;     // k is (B,2,1) float32
    long long n4_ll = B * 16;                // 64 floats = 16 float4 per record
    const long long n4_guar = (long long)out_size / 4;   // guaranteed floats/4
    if (n4_guar > 0 && n4_guar < n4_ll) n4_ll = n4_guar;
    if (n4_ll <= 0) return;
    const int n4 = (int)n4_ll;
    const int block = 256;
    const int grid = (int)((n4_ll + block - 1) / block);
    bulk_hamiltonian_real_kernel<<<grid, block, 0, stream>>>(k, (vf4*)d_out, n4);
}